// Round 13
// baseline (234.541 us; speedup 1.0000x reference)
//
#include <hip/hip_runtime.h>
#include <stdint.h>

#define DM 1024
#define SEQ 2048
#define MTOT 8192   // 4*2048

typedef __attribute__((ext_vector_type(8))) short bf16x8;
typedef __attribute__((ext_vector_type(4))) float f32x4;
typedef __attribute__((ext_vector_type(16))) float f32x16;
typedef __attribute__((ext_vector_type(8))) unsigned short u16x8;
typedef __attribute__((ext_vector_type(4))) unsigned short u16x4;
typedef __attribute__((ext_vector_type(4))) uint32_t u32x4;

__device__ __forceinline__ unsigned short f2bf(float x) {
  uint32_t u = __builtin_bit_cast(uint32_t, x);
  u += 0x7fffu + ((u >> 16) & 1u);   // RTNE
  return (unsigned short)(u >> 16);
}

__device__ __forceinline__ uint32_t cvtpk_bf16(float lo, float hi) {
  uint32_t r;
  asm("v_cvt_pk_bf16_f32 %0, %1, %2" : "=v"(r) : "v"(lo), "v"(hi));
  return r;
}

__device__ __forceinline__ void gload16(void* lds, const void* g) {
  __builtin_amdgcn_global_load_lds(
      (const __attribute__((address_space(1))) void*)(uintptr_t)g,
      (__attribute__((address_space(3))) void*)(uintptr_t)lds,
      16, 0, 0);
}

// ---------------- weight transpose + bf16 convert: Wt[n][k] = bf16(W[k][n])
__global__ __launch_bounds__(256)
void prep_w(const float* __restrict__ w0, const float* __restrict__ w1,
            const float* __restrict__ w2, const float* __restrict__ w3,
            unsigned short* __restrict__ Wt) {
  const int z = blockIdx.z;
  const float* W = z == 0 ? w0 : z == 1 ? w1 : z == 2 ? w2 : w3;
  unsigned short* out = Wt + (size_t)z * 1048576;
  __shared__ float tile[32][33];
  const int n0 = blockIdx.x * 32, k0 = blockIdx.y * 32;
  const int tx = threadIdx.x & 31, ty = threadIdx.x >> 5;
#pragma unroll
  for (int j = 0; j < 32; j += 8)
    tile[ty + j][tx] = W[(size_t)(k0 + ty + j) * DM + n0 + tx];
  __syncthreads();
#pragma unroll
  for (int j = 0; j < 32; j += 8)
    out[(size_t)(n0 + ty + j) * DM + k0 + tx] = f2bf(tile[tx][ty + j]);
}

// ---------------- bf16 GEMM core (128x128 tile, BK=64, 4 waves)
// MODE 1: f32 row-major out (used for final projection; A is bf16)
template <int MODE>
__global__ __launch_bounds__(256)
void gemm_bt(const unsigned short* __restrict__ A,
             const unsigned short* __restrict__ Wt,
             const float* __restrict__ bias,
             void* __restrict__ C, float oscale) {
  __shared__ char sA[16384];   // [128 rows][64 bf16 = 128B], XOR-swizzled
  __shared__ char sB[16384];
  const int t = threadIdx.x, wave = t >> 6, lane = t & 63;
  const int m0 = blockIdx.x * 128, n0 = blockIdx.y * 128;
  const int wr = (wave >> 1) * 64, wc = (wave & 1) * 64;
  const int lr = lane & 15, kg = lane >> 4;

  f32x4 acc[4][4];
#pragma unroll
  for (int i = 0; i < 4; ++i)
#pragma unroll
    for (int j = 0; j < 4; ++j) acc[i][j] = (f32x4){0.f, 0.f, 0.f, 0.f};

  for (int kt = 0; kt < 16; ++kt) {
    __syncthreads();
#pragma unroll
    for (int i = 0; i < 4; ++i) {
      int c = wave * 4 + i;
      int row = c * 8 + (lane >> 3);
      int bo = ((lane & 7) * 16) ^ ((row & 7) << 4);
      gload16(&sA[c * 1024], (const char*)(A + (size_t)(m0 + row) * DM + kt * 64) + bo);
      gload16(&sB[c * 1024], (const char*)(Wt + (size_t)(n0 + row) * DM + kt * 64) + bo);
    }
    __syncthreads();
#pragma unroll
    for (int ks = 0; ks < 2; ++ks) {
      bf16x8 afr[4], bfr[4];
#pragma unroll
      for (int j = 0; j < 4; ++j) {
        int mr = wr + j * 16 + lr;
        afr[j] = *(const bf16x8*)&sA[mr * 128 + ((ks * 64 + kg * 16) ^ ((mr & 7) << 4))];
        int nr = wc + j * 16 + lr;
        bfr[j] = *(const bf16x8*)&sB[nr * 128 + ((ks * 64 + kg * 16) ^ ((nr & 7) << 4))];
      }
#pragma unroll
      for (int mi = 0; mi < 4; ++mi)
#pragma unroll
        for (int nj = 0; nj < 4; ++nj)
          acc[mi][nj] = __builtin_amdgcn_mfma_f32_16x16x32_bf16(afr[mi], bfr[nj], acc[mi][nj], 0, 0, 0);
    }
  }
  // epilogue: C/D layout col=lane&15, row=(lane>>4)*4+r
#pragma unroll
  for (int nj = 0; nj < 4; ++nj) {
    int col = n0 + wc + nj * 16 + lr;
    float bv = bias[col];
#pragma unroll
    for (int mi = 0; mi < 4; ++mi) {
      int rowseq = m0 + wr + mi * 16 + kg * 4;
#pragma unroll
      for (int r = 0; r < 4; ++r) {
        float v = (acc[mi][nj][r] + bv) * oscale;
        if (MODE == 1) ((float*)C)[(size_t)(rowseq + r) * DM + col] = v;
        else ((unsigned short*)C)[(size_t)(rowseq + r) * DM + col] = f2bf(v);
      }
    }
  }
}

// ---------------- batched QKV projection with FUSED fp32->bf16 A-staging.
// grid (64, 8, 3); z -> {Q,K,V}. A side: reg-staged (f32 load -> f2bf ->
// ds_write_b128 into the identical swizzled LDS image gload16 would build:
// dest = sA + c*1024 + lane*16; source col (bf16 units) = bo/2 =
// (lane&7)*8 ^ ((row&7)<<3), exact since both terms even). B: gload16.
// Eliminates the separate cvt3 pass (~150MB HBM round trip).
__global__ __launch_bounds__(256)
void gemm_qkv(const float* __restrict__ Xq, const float* __restrict__ Xk,
              const float* __restrict__ Xv,
              const unsigned short* __restrict__ Wt,     // [3*1024][1024]
              const float* __restrict__ bq, const float* __restrict__ bk,
              const float* __restrict__ bv,
              unsigned short* __restrict__ Qb, unsigned short* __restrict__ Kb,
              unsigned short* __restrict__ Vt, float qscale) {
  __shared__ char sA[16384];
  __shared__ char sB[16384];
  const int z = blockIdx.z;
  const float* Xf = z == 0 ? Xq : z == 1 ? Xk : Xv;
  const unsigned short* W = Wt + (size_t)z * 1048576;
  const float* bias = z == 0 ? bq : z == 1 ? bk : bv;
  const int t = threadIdx.x, wave = t >> 6, lane = t & 63;
  const int m0 = blockIdx.x * 128, n0 = blockIdx.y * 128;
  const int wr = (wave >> 1) * 64, wc = (wave & 1) * 64;
  const int lr = lane & 15, kg = lane >> 4;

  f32x4 acc[4][4];
#pragma unroll
  for (int i = 0; i < 4; ++i)
#pragma unroll
    for (int j = 0; j < 4; ++j) acc[i][j] = (f32x4){0.f, 0.f, 0.f, 0.f};

  for (int kt = 0; kt < 16; ++kt) {
    __syncthreads();
    // B tile via global_load_lds
#pragma unroll
    for (int i = 0; i < 4; ++i) {
      int c = wave * 4 + i;
      int row = c * 8 + (lane >> 3);
      int bo = ((lane & 7) * 16) ^ ((row & 7) << 4);
      gload16(&sB[c * 1024], (const char*)(W + (size_t)(n0 + row) * DM + kt * 64) + bo);
    }
    // A tile: reg-staged f32 -> bf16 -> swizzled LDS image
#pragma unroll
    for (int i = 0; i < 4; ++i) {
      int c = wave * 4 + i;
      int row = c * 8 + (lane >> 3);
      int colf = ((lane & 7) * 8) ^ ((row & 7) << 3);
      const float* src = Xf + (size_t)(m0 + row) * DM + kt * 64 + colf;
      f32x4 a = *(const f32x4*)src;
      f32x4 b2 = *(const f32x4*)(src + 4);
      u16x8 pk;
#pragma unroll
      for (int j = 0; j < 4; ++j) { pk[j] = f2bf(a[j]); pk[4 + j] = f2bf(b2[j]); }
      *(u16x8*)&sA[c * 1024 + lane * 16] = pk;
    }
    __syncthreads();
#pragma unroll
    for (int ks = 0; ks < 2; ++ks) {
      bf16x8 afr[4], bfr[4];
#pragma unroll
      for (int j = 0; j < 4; ++j) {
        int mr = wr + j * 16 + lr;
        afr[j] = *(const bf16x8*)&sA[mr * 128 + ((ks * 64 + kg * 16) ^ ((mr & 7) << 4))];
        int nr = wc + j * 16 + lr;
        bfr[j] = *(const bf16x8*)&sB[nr * 128 + ((ks * 64 + kg * 16) ^ ((nr & 7) << 4))];
      }
#pragma unroll
      for (int mi = 0; mi < 4; ++mi)
#pragma unroll
        for (int nj = 0; nj < 4; ++nj)
          acc[mi][nj] = __builtin_amdgcn_mfma_f32_16x16x32_bf16(afr[mi], bfr[nj], acc[mi][nj], 0, 0, 0);
    }
  }
  const float sc = z == 0 ? qscale : 1.0f;
#pragma unroll
  for (int nj = 0; nj < 4; ++nj) {
    int col = n0 + wc + nj * 16 + lr;
    float bvv = bias[col];
#pragma unroll
    for (int mi = 0; mi < 4; ++mi) {
      int rowseq = m0 + wr + mi * 16 + kg * 4;
      if (z == 2) {
        u16x4 pk;
#pragma unroll
        for (int r = 0; r < 4; ++r) pk[r] = f2bf(acc[mi][nj][r] + bvv);
        *(u16x4*)(Vt + ((size_t)((rowseq >> 11) << 10) + col) * SEQ + (rowseq & 2047)) = pk;
      } else {
        unsigned short* out = z == 0 ? Qb : Kb;
#pragma unroll
        for (int r = 0; r < 4; ++r)
          out[(size_t)(rowseq + r) * DM + col] = f2bf((acc[mi][nj][r] + bvv) * sc);
      }
    }
  }
}

// ---------------- flash attention, swapped-operand 32x32x16, fixed-max,
// dual q-group per wave (64 q), 4-WAVE BLOCKS: grid (64 bh, 8 q-tiles) =
// 512 blocks = 2 blocks/CU (LDS 64KB x2 = 128 <= 160KB). Two independent
// blocks per CU overlap each other's pair-barrier drains (single-block R12
// left the CU idle at every barrier: 1 block/CU, 2 waves/SIMD, 92.6us at a
// 27.5us MFMA floor). Staging: R8-proven 2-chunk macro per wave per tile.
// Fixed-max softmax: p = 2^(s-12), -12 in MFMA C-init (R11-proven).
// P-exchange: proven shfl_xor(32)+select ONLY (permlane: R7/R10 burns).
__global__ __launch_bounds__(256)
void attn(const unsigned short* __restrict__ Qb,
          const unsigned short* __restrict__ Kb,
          const unsigned short* __restrict__ Vt,
          unsigned short* __restrict__ Ctx) {
  __shared__ char sK[4][8192];   // [64 key][64 d] each, swizzled
  __shared__ char sV[4][8192];   // [64 d][64 key] each, swizzled
  const int t = threadIdx.x, wave = t >> 6, lane = t & 63;
  const int l31 = lane & 31, hi = lane >> 5;
  const int bh = blockIdx.x, b = bh >> 4, h = bh & 15;
  const int q0 = blockIdx.y * 256;

  // staging: wave w owns chunks 2w,2w+1 (rows w*16..w*16+15) of K and V
  const int srow = wave * 16 + (lane >> 3);
  const int sbo = ((lane & 7) * 16) ^ ((srow & 7) << 4);  // (srow+8)&7 == srow&7
  const char* gK = (const char*)Kb + ((size_t)b * SEQ + srow) * (DM * 2) + h * 128 + sbo;
  const char* gV = (const char*)Vt + ((size_t)bh * 64 + srow) * (SEQ * 2) + sbo;

#define STAGE1(buf, kt) do { \
    gload16(&sK[buf][wave * 2048],        gK + (size_t)(kt) * 131072); \
    gload16(&sK[buf][wave * 2048 + 1024], gK + (size_t)(kt) * 131072 + 16384); \
    gload16(&sV[buf][wave * 2048],        gV + (size_t)(kt) * 128); \
    gload16(&sV[buf][wave * 2048 + 1024], gV + (size_t)(kt) * 128 + 32768); \
  } while (0)

  // Q B-frags, two groups: qA = q0+wave*64+l31, qB = qA+32
  bf16x8 qfA[4], qfB[4];
  {
    const unsigned short* qpA = Qb + ((size_t)b * SEQ + q0 + wave * 64 + l31) * DM + h * 64 + hi * 8;
    const unsigned short* qpB = qpA + (size_t)32 * DM;
#pragma unroll
    for (int ks = 0; ks < 4; ++ks) {
      qfA[ks] = *(const bf16x8*)(qpA + ks * 16);
      qfB[ks] = *(const bf16x8*)(qpB + ks * 16);
    }
  }

  f32x16 oA0, oA1, oB0, oB1, mInit;
#pragma unroll
  for (int i = 0; i < 16; ++i) {
    oA0[i] = 0.f; oA1[i] = 0.f; oB0[i] = 0.f; oB1[i] = 0.f; mInit[i] = -12.0f;
  }
  float lA = 0.f, lB = 0.f;   // own-half partials; cross-half summed at end

  STAGE1(0, 0);
  STAGE1(1, 1);
  __syncthreads();

  for (int p = 0; p < SEQ / 128; ++p) {
    if (p + 1 < SEQ / 128) {
      const int nt = 2 * p + 2;
      STAGE1(nt & 3, nt);
      STAGE1((nt + 1) & 3, nt + 1);
    }
#pragma unroll
    for (int half = 0; half < 2; ++half) {
      const int buf = 2 * (p & 1) + half;

      // ---- S^T = K . Q - 12 for both q-groups (kf read once, used twice)
      f32x16 sA0 = mInit, sA1 = mInit, sB0 = mInit, sB1 = mInit;
      const char* kbase = sK[buf];
      __builtin_amdgcn_s_setprio(1);
#pragma unroll
      for (int ks = 0; ks < 4; ++ks) {
        const int swz = (ks * 32 + hi * 16) ^ ((l31 & 7) << 4);
        bf16x8 kf0 = *(const bf16x8*)(kbase + l31 * 128 + swz);
        bf16x8 kf1 = *(const bf16x8*)(kbase + (32 + l31) * 128 + swz);
        sA0 = __builtin_amdgcn_mfma_f32_32x32x16_bf16(kf0, qfA[ks], sA0, 0, 0, 0);
        sB0 = __builtin_amdgcn_mfma_f32_32x32x16_bf16(kf0, qfB[ks], sB0, 0, 0, 0);
        sA1 = __builtin_amdgcn_mfma_f32_32x32x16_bf16(kf1, qfA[ks], sA1, 0, 0, 0);
        sB1 = __builtin_amdgcn_mfma_f32_32x32x16_bf16(kf1, qfB[ks], sB1, 0, 0, 0);
      }
      __builtin_amdgcn_s_setprio(0);

      // ---- p = 2^s, parallel partial sums (groups independent)
      {
        float a0 = 0.f, a1 = 0.f, b0 = 0.f, b1 = 0.f;
#pragma unroll
        for (int i = 0; i < 16; i += 2) {
          float pa0 = __builtin_amdgcn_exp2f(sA0[i + 0]); sA0[i + 0] = pa0; a0 += pa0;
          float pa1 = __builtin_amdgcn_exp2f(sA0[i + 1]); sA0[i + 1] = pa1; a1 += pa1;
          float pb0 = __builtin_amdgcn_exp2f(sB0[i + 0]); sB0[i + 0] = pb0; b0 += pb0;
          float pb1 = __builtin_amdgcn_exp2f(sB0[i + 1]); sB0[i + 1] = pb1; b1 += pb1;
        }
#pragma unroll
        for (int i = 0; i < 16; i += 2) {
          float pa0 = __builtin_amdgcn_exp2f(sA1[i + 0]); sA1[i + 0] = pa0; a0 += pa0;
          float pa1 = __builtin_amdgcn_exp2f(sA1[i + 1]); sA1[i + 1] = pa1; a1 += pa1;
          float pb0 = __builtin_amdgcn_exp2f(sB1[i + 0]); sB1[i + 0] = pb0; b0 += pb0;
          float pb1 = __builtin_amdgcn_exp2f(sB1[i + 1]); sB1[i + 1] = pb1; b1 += pb1;
        }
        lA += a0 + a1;
        lB += b0 + b1;
      }

      // ---- O^T += Vt . P^T  (vf read once, used by both groups)
      const char* vbase = sV[buf];
#pragma unroll
      for (int sl = 0; sl < 4; ++sl) {
        const f32x16& spA = (sl < 2) ? sA0 : sA1;
        const f32x16& spB = (sl < 2) ? sB0 : sB1;
        const int s8 = (sl & 1) * 8;
        // group A exchange
        uint32_t ax0 = cvtpk_bf16(spA[s8 + 0], spA[s8 + 1]);
        uint32_t ax1 = cvtpk_bf16(spA[s8 + 2], spA[s8 + 3]);
        uint32_t ay0 = cvtpk_bf16(spA[s8 + 4], spA[s8 + 5]);
        uint32_t ay1 = cvtpk_bf16(spA[s8 + 6], spA[s8 + 7]);
        uint32_t ax0s = (uint32_t)__shfl_xor((int)ax0, 32);
        uint32_t ax1s = (uint32_t)__shfl_xor((int)ax1, 32);
        uint32_t ay0s = (uint32_t)__shfl_xor((int)ay0, 32);
        uint32_t ay1s = (uint32_t)__shfl_xor((int)ay1, 32);
        u32x4 wvA;
        wvA[0] = hi ? ay0s : ax0;
        wvA[1] = hi ? ay1s : ax1;
        wvA[2] = hi ? ay0 : ax0s;
        wvA[3] = hi ? ay1 : ax1s;
        bf16x8 pfA = __builtin_bit_cast(bf16x8, wvA);
        // group B exchange
        uint32_t bx0 = cvtpk_bf16(spB[s8 + 0], spB[s8 + 1]);
        uint32_t bx1 = cvtpk_bf16(spB[s8 + 2], spB[s8 + 3]);
        uint32_t by0 = cvtpk_bf16(spB[s8 + 4], spB[s8 + 5]);
        uint32_t by1 = cvtpk_bf16(spB[s8 + 6], spB[s8 + 7]);
        uint32_t bx0s = (uint32_t)__shfl_xor((int)bx0, 32);
        uint32_t bx1s = (uint32_t)__shfl_xor((int)bx1, 32);
        uint32_t by0s = (uint32_t)__shfl_xor((int)by0, 32);
        uint32_t by1s = (uint32_t)__shfl_xor((int)by1, 32);
        u32x4 wvB;
        wvB[0] = hi ? by0s : bx0;
        wvB[1] = hi ? by1s : bx1;
        wvB[2] = hi ? by0 : bx0s;
        wvB[3] = hi ? by1 : bx1s;
        bf16x8 pfB = __builtin_bit_cast(bf16x8, wvB);

        const int swz = (sl * 32 + hi * 16) ^ ((l31 & 7) << 4);
        bf16x8 vf0 = *(const bf16x8*)(vbase + l31 * 128 + swz);
        bf16x8 vf1 = *(const bf16x8*)(vbase + (32 + l31) * 128 + swz);
        __builtin_amdgcn_s_setprio(1);
        oA0 = __builtin_amdgcn_mfma_f32_32x32x16_bf16(vf0, pfA, oA0, 0, 0, 0);
        oB0 = __builtin_amdgcn_mfma_f32_32x32x16_bf16(vf0, pfB, oB0, 0, 0, 0);
        oA1 = __builtin_amdgcn_mfma_f32_32x32x16_bf16(vf1, pfA, oA1, 0, 0, 0);
        oB1 = __builtin_amdgcn_mfma_f32_32x32x16_bf16(vf1, pfB, oB1, 0, 0, 0);
        __builtin_amdgcn_s_setprio(0);
      }
    }
    __syncthreads();
  }
#undef STAGE1

  // ---- epilogue: O^T[d][q], lane q = l31; d = dt*32 + rg*8 + hi*4 + i
  float ltA = lA + __shfl_xor(lA, 32);
  float ltB = lB + __shfl_xor(lB, 32);
  float invA = 1.0f / ltA, invB = 1.0f / ltB;
  unsigned short* orowA = Ctx + ((size_t)b * SEQ + q0 + wave * 64 + l31) * DM + h * 64;
  unsigned short* orowB = orowA + (size_t)32 * DM;
#pragma unroll
  for (int dt = 0; dt < 2; ++dt) {
    const f32x16& oa = dt ? oA1 : oA0;
    const f32x16& ob = dt ? oB1 : oB0;
#pragma unroll
    for (int rg = 0; rg < 4; ++rg) {
      u16x4 pkA, pkB;
#pragma unroll
      for (int i = 0; i < 4; ++i) {
        pkA[i] = f2bf(oa[rg * 4 + i] * invA);
        pkB[i] = f2bf(ob[rg * 4 + i] * invB);
      }
      *(u16x4*)(orowA + dt * 32 + rg * 8 + hi * 4) = pkA;
      *(u16x4*)(orowB + dt * 32 + rg * 8 + hi * 4) = pkB;
    }
  }
}

extern "C" void kernel_launch(void* const* d_in, const int* in_sizes, int n_in,
                              void* d_out, int out_size, void* d_ws, size_t ws_size,
                              hipStream_t stream) {
  const float* query = (const float*)d_in[0];
  const float* key   = (const float*)d_in[1];
  const float* value = (const float*)d_in[2];
  const float* Wq = (const float*)d_in[3];
  const float* bq = (const float*)d_in[4];
  const float* Wk = (const float*)d_in[5];
  const float* bk = (const float*)d_in[6];
  const float* Wv = (const float*)d_in[7];
  const float* bv = (const float*)d_in[8];
  const float* Wo = (const float*)d_in[9];
  const float* bo = (const float*)d_in[10];

  const float QSCALE = 0.125f * 1.44269504088896340736f;
  char* ws = (char*)d_ws;
  const size_t MB = 1048576;

  // layout (72MB): Wt@0 (8MB), Qb@8, Kb@24, Vt@40, Xc@56 (16MB each)
  unsigned short* Wt = (unsigned short*)ws;
  unsigned short* Qb = (unsigned short*)(ws + 8 * MB);
  unsigned short* Kb = (unsigned short*)(ws + 24 * MB);
  unsigned short* Vt = (unsigned short*)(ws + 40 * MB);
  unsigned short* Xc = (unsigned short*)(ws + 56 * MB);

  prep_w<<<dim3(32, 32, 4), 256, 0, stream>>>(Wq, Wk, Wv, Wo, Wt);

  gemm_qkv<<<dim3(64, 8, 3), 256, 0, stream>>>(query, key, value, Wt,
                                               bq, bk, bv, Qb, Kb, Vt, QSCALE);

  attn<<<dim3(64, 8), 256, 0, stream>>>(Qb, Kb, Vt, Xc);

  gemm_bt<1><<<dim3(64, 8), 256, 0, stream>>>(Xc, Wt + (size_t)3 * 1048576, bo, d_out, 1.0f);
}

// Round 14
// 190.568 us; speedup vs baseline: 1.2307x; 1.2307x over previous
//
#include <hip/hip_runtime.h>
#include <stdint.h>

#define DM 1024
#define SEQ 2048
#define MTOT 8192   // 4*2048

typedef __attribute__((ext_vector_type(8))) short bf16x8;
typedef __attribute__((ext_vector_type(4))) float f32x4;
typedef __attribute__((ext_vector_type(16))) float f32x16;
typedef __attribute__((ext_vector_type(8))) unsigned short u16x8;
typedef __attribute__((ext_vector_type(4))) unsigned short u16x4;
typedef __attribute__((ext_vector_type(4))) uint32_t u32x4;
typedef __attribute__((ext_vector_type(2))) unsigned int u32x2;

__device__ __forceinline__ unsigned short f2bf(float x) {
  uint32_t u = __builtin_bit_cast(uint32_t, x);
  u += 0x7fffu + ((u >> 16) & 1u);   // RTNE
  return (unsigned short)(u >> 16);
}

__device__ __forceinline__ uint32_t cvtpk_bf16(float lo, float hi) {
  uint32_t r;
  asm("v_cvt_pk_bf16_f32 %0, %1, %2" : "=v"(r) : "v"(lo), "v"(hi));
  return r;
}

__device__ __forceinline__ void gload16(void* lds, const void* g) {
  __builtin_amdgcn_global_load_lds(
      (const __attribute__((address_space(1))) void*)(uintptr_t)g,
      (__attribute__((address_space(3))) void*)(uintptr_t)lds,
      16, 0, 0);
}

// ---------------- weight transpose + bf16 convert: Wt[n][k] = bf16(W[k][n])
__global__ __launch_bounds__(256)
void prep_w(const float* __restrict__ w0, const float* __restrict__ w1,
            const float* __restrict__ w2, const float* __restrict__ w3,
            unsigned short* __restrict__ Wt) {
  const int z = blockIdx.z;
  const float* W = z == 0 ? w0 : z == 1 ? w1 : z == 2 ? w2 : w3;
  unsigned short* out = Wt + (size_t)z * 1048576;
  __shared__ float tile[32][33];
  const int n0 = blockIdx.x * 32, k0 = blockIdx.y * 32;
  const int tx = threadIdx.x & 31, ty = threadIdx.x >> 5;
#pragma unroll
  for (int j = 0; j < 32; j += 8)
    tile[ty + j][tx] = W[(size_t)(k0 + ty + j) * DM + n0 + tx];
  __syncthreads();
#pragma unroll
  for (int j = 0; j < 32; j += 8)
    out[(size_t)(n0 + ty + j) * DM + k0 + tx] = f2bf(tile[tx][ty + j]);
}

// ---------------- fp32 -> bf16, three inputs in one dispatch (grid.y = z)
__global__ __launch_bounds__(256)
void cvt3(const float* __restrict__ q, const float* __restrict__ k,
          const float* __restrict__ v, unsigned short* __restrict__ out) {
  const int z = blockIdx.y;
  const float* in = z == 0 ? q : z == 1 ? k : v;
  unsigned short* o = out + (size_t)z * MTOT * DM;
  int i = blockIdx.x * 256 + threadIdx.x;   // grid.x = 4096 -> exact cover
  f32x4 a = *(const f32x4*)(in + (size_t)i * 8);
  f32x4 b = *(const f32x4*)(in + (size_t)i * 8 + 4);
  u16x8 ov;
#pragma unroll
  for (int j = 0; j < 4; ++j) { ov[j] = f2bf(a[j]); ov[4 + j] = f2bf(b[j]); }
  *(u16x8*)(o + (size_t)i * 8) = ov;
}

// ---------------- bf16 GEMM core (128x128 tile, BK=64, 4 waves)
// MODE 0: bf16 row-major out (scaled); MODE 1: f32 row-major;
// MODE 2: bf16 V-transposed Vt[(b*16+h)*64+d][s]
template <int MODE>
__global__ __launch_bounds__(256)
void gemm_bt(const unsigned short* __restrict__ A,
             const unsigned short* __restrict__ Wt,
             const float* __restrict__ bias,
             void* __restrict__ C, float oscale) {
  __shared__ char sA[16384];   // [128 rows][64 bf16 = 128B], XOR-swizzled
  __shared__ char sB[16384];
  const int t = threadIdx.x, wave = t >> 6, lane = t & 63;
  const int m0 = blockIdx.x * 128, n0 = blockIdx.y * 128;
  const int wr = (wave >> 1) * 64, wc = (wave & 1) * 64;
  const int lr = lane & 15, kg = lane >> 4;

  f32x4 acc[4][4];
#pragma unroll
  for (int i = 0; i < 4; ++i)
#pragma unroll
    for (int j = 0; j < 4; ++j) acc[i][j] = (f32x4){0.f, 0.f, 0.f, 0.f};

  for (int kt = 0; kt < 16; ++kt) {
    __syncthreads();
#pragma unroll
    for (int i = 0; i < 4; ++i) {
      int c = wave * 4 + i;
      int row = c * 8 + (lane >> 3);
      int bo = ((lane & 7) * 16) ^ ((row & 7) << 4);
      gload16(&sA[c * 1024], (const char*)(A + (size_t)(m0 + row) * DM + kt * 64) + bo);
      gload16(&sB[c * 1024], (const char*)(Wt + (size_t)(n0 + row) * DM + kt * 64) + bo);
    }
    __syncthreads();
#pragma unroll
    for (int ks = 0; ks < 2; ++ks) {
      bf16x8 afr[4], bfr[4];
#pragma unroll
      for (int j = 0; j < 4; ++j) {
        int mr = wr + j * 16 + lr;
        afr[j] = *(const bf16x8*)&sA[mr * 128 + ((ks * 64 + kg * 16) ^ ((mr & 7) << 4))];
        int nr = wc + j * 16 + lr;
        bfr[j] = *(const bf16x8*)&sB[nr * 128 + ((ks * 64 + kg * 16) ^ ((nr & 7) << 4))];
      }
#pragma unroll
      for (int mi = 0; mi < 4; ++mi)
#pragma unroll
        for (int nj = 0; nj < 4; ++nj)
          acc[mi][nj] = __builtin_amdgcn_mfma_f32_16x16x32_bf16(afr[mi], bfr[nj], acc[mi][nj], 0, 0, 0);
    }
  }
  // epilogue: C/D layout col=lane&15, row=(lane>>4)*4+r
#pragma unroll
  for (int nj = 0; nj < 4; ++nj) {
    int col = n0 + wc + nj * 16 + lr;
    float bv = bias[col];
#pragma unroll
    for (int mi = 0; mi < 4; ++mi) {
      int rowseq = m0 + wr + mi * 16 + kg * 4;
      if (MODE == 2) {
        u16x4 pk;
#pragma unroll
        for (int r = 0; r < 4; ++r) pk[r] = f2bf(acc[mi][nj][r] + bv);
        *(u16x4*)((unsigned short*)C +
                  ((size_t)((rowseq >> 11) << 10) + col) * SEQ + (rowseq & 2047)) = pk;
      } else {
#pragma unroll
        for (int r = 0; r < 4; ++r) {
          float v = (acc[mi][nj][r] + bv) * oscale;
          if (MODE == 1) ((float*)C)[(size_t)(rowseq + r) * DM + col] = v;
          else ((unsigned short*)C)[(size_t)(rowseq + r) * DM + col] = f2bf(v);
        }
      }
    }
  }
}

// ---------------- batched QKV projection: grid (64, 8, 3); z -> {Q,K,V}
__global__ __launch_bounds__(256)
void gemm_qkv(const unsigned short* __restrict__ Xall,   // [3][8192][1024]
              const unsigned short* __restrict__ Wt,     // [3*1024][1024]
              const float* __restrict__ bq, const float* __restrict__ bk,
              const float* __restrict__ bv,
              unsigned short* __restrict__ Qb, unsigned short* __restrict__ Kb,
              unsigned short* __restrict__ Vt, float qscale) {
  __shared__ char sA[16384];
  __shared__ char sB[16384];
  const int z = blockIdx.z;
  const unsigned short* A = Xall + (size_t)z * MTOT * DM;
  const unsigned short* W = Wt + (size_t)z * 1048576;
  const float* bias = z == 0 ? bq : z == 1 ? bk : bv;
  const int t = threadIdx.x, wave = t >> 6, lane = t & 63;
  const int m0 = blockIdx.x * 128, n0 = blockIdx.y * 128;
  const int wr = (wave >> 1) * 64, wc = (wave & 1) * 64;
  const int lr = lane & 15, kg = lane >> 4;

  f32x4 acc[4][4];
#pragma unroll
  for (int i = 0; i < 4; ++i)
#pragma unroll
    for (int j = 0; j < 4; ++j) acc[i][j] = (f32x4){0.f, 0.f, 0.f, 0.f};

  for (int kt = 0; kt < 16; ++kt) {
    __syncthreads();
#pragma unroll
    for (int i = 0; i < 4; ++i) {
      int c = wave * 4 + i;
      int row = c * 8 + (lane >> 3);
      int bo = ((lane & 7) * 16) ^ ((row & 7) << 4);
      gload16(&sA[c * 1024], (const char*)(A + (size_t)(m0 + row) * DM + kt * 64) + bo);
      gload16(&sB[c * 1024], (const char*)(W + (size_t)(n0 + row) * DM + kt * 64) + bo);
    }
    __syncthreads();
#pragma unroll
    for (int ks = 0; ks < 2; ++ks) {
      bf16x8 afr[4], bfr[4];
#pragma unroll
      for (int j = 0; j < 4; ++j) {
        int mr = wr + j * 16 + lr;
        afr[j] = *(const bf16x8*)&sA[mr * 128 + ((ks * 64 + kg * 16) ^ ((mr & 7) << 4))];
        int nr = wc + j * 16 + lr;
        bfr[j] = *(const bf16x8*)&sB[nr * 128 + ((ks * 64 + kg * 16) ^ ((nr & 7) << 4))];
      }
#pragma unroll
      for (int mi = 0; mi < 4; ++mi)
#pragma unroll
        for (int nj = 0; nj < 4; ++nj)
          acc[mi][nj] = __builtin_amdgcn_mfma_f32_16x16x32_bf16(afr[mi], bfr[nj], acc[mi][nj], 0, 0, 0);
    }
  }
  const float sc = z == 0 ? qscale : 1.0f;
#pragma unroll
  for (int nj = 0; nj < 4; ++nj) {
    int col = n0 + wc + nj * 16 + lr;
    float bvv = bias[col];
#pragma unroll
    for (int mi = 0; mi < 4; ++mi) {
      int rowseq = m0 + wr + mi * 16 + kg * 4;
      if (z == 2) {
        u16x4 pk;
#pragma unroll
        for (int r = 0; r < 4; ++r) pk[r] = f2bf(acc[mi][nj][r] + bvv);
        *(u16x4*)(Vt + ((size_t)((rowseq >> 11) << 10) + col) * SEQ + (rowseq & 2047)) = pk;
      } else {
        unsigned short* out = z == 0 ? Qb : Kb;
#pragma unroll
        for (int r = 0; r < 4; ++r)
          out[(size_t)(rowseq + r) * DM + col] = f2bf((acc[mi][nj][r] + bvv) * sc);
      }
    }
  }
}

// ---------------- flash attention, swapped-operand 32x32x16, fixed-max,
// dual q-group per wave (64 q), 8 waves, grid (64 bh, 4 q-tiles) -- the
// R12-proven shape (92.6us). THIS ROUND: P-exchange via permlane32_swap
// (VALU) instead of 32 ds_bpermute + 32 cndmask per half-tile, relieving
// the LDS pipe (~3K cyc/iter/CU, its largest single consumer).
// Semantics pinned by R10's failure + R11's fixed-max exoneration:
//   r = permlane32_swap(a, b) => r[0] = {a.lo | b.lo}, r[1] = {a.hi | b.hi}
// (swaps a's upper half with b's lower half). With a=x0 (own keys base+0,1)
// and b=y0 (own keys base+8,9): r[0] = wv[0], r[1] = wv[2] exactly.
// Operands are always distinct values -> no R7 tied-operand coalescing.
// Fixed-max softmax: p = 2^(s-12), -12 in MFMA C-init (R11-proven).
__global__ __launch_bounds__(512)
void attn(const unsigned short* __restrict__ Qb,
          const unsigned short* __restrict__ Kb,
          const unsigned short* __restrict__ Vt,
          unsigned short* __restrict__ Ctx) {
  __shared__ char sK[4][8192];   // [64 key][64 d] each, swizzled
  __shared__ char sV[4][8192];   // [64 d][64 key] each, swizzled
  const int t = threadIdx.x, wave = t >> 6, lane = t & 63;
  const int l31 = lane & 31, hi = lane >> 5;
  const int bh = blockIdx.x, b = bh >> 4, h = bh & 15;
  const int q0 = blockIdx.y * 512;

  // staging: wave w owns chunk w (8 rows, 1KB) of each tile
  const int srow = wave * 8 + (lane >> 3);
  const int sbo = ((lane & 7) * 16) ^ ((srow & 7) << 4);
  const char* gK = (const char*)Kb + ((size_t)b * SEQ + srow) * (DM * 2) + h * 128 + sbo;
  const char* gV = (const char*)Vt + ((size_t)bh * 64 + srow) * (SEQ * 2) + sbo;

#define STAGE1(buf, kt) do { \
    gload16(&sK[buf][wave * 1024], gK + (size_t)(kt) * 131072); \
    gload16(&sV[buf][wave * 1024], gV + (size_t)(kt) * 128); \
  } while (0)

  // Q B-frags, two groups: qA = q0+wave*64+l31, qB = qA+32
  bf16x8 qfA[4], qfB[4];
  {
    const unsigned short* qpA = Qb + ((size_t)b * SEQ + q0 + wave * 64 + l31) * DM + h * 64 + hi * 8;
    const unsigned short* qpB = qpA + (size_t)32 * DM;
#pragma unroll
    for (int ks = 0; ks < 4; ++ks) {
      qfA[ks] = *(const bf16x8*)(qpA + ks * 16);
      qfB[ks] = *(const bf16x8*)(qpB + ks * 16);
    }
  }

  f32x16 oA0, oA1, oB0, oB1, mInit;
#pragma unroll
  for (int i = 0; i < 16; ++i) {
    oA0[i] = 0.f; oA1[i] = 0.f; oB0[i] = 0.f; oB1[i] = 0.f; mInit[i] = -12.0f;
  }
  float lA = 0.f, lB = 0.f;   // own-half partials; cross-half summed at end

  STAGE1(0, 0);
  STAGE1(1, 1);
  __syncthreads();

  for (int p = 0; p < SEQ / 128; ++p) {
    if (p + 1 < SEQ / 128) {
      const int nt = 2 * p + 2;
      STAGE1(nt & 3, nt);
      STAGE1((nt + 1) & 3, nt + 1);
    }
#pragma unroll
    for (int half = 0; half < 2; ++half) {
      const int buf = 2 * (p & 1) + half;

      // ---- S^T = K . Q - 12 for both q-groups (kf read once, used twice)
      f32x16 sA0 = mInit, sA1 = mInit, sB0 = mInit, sB1 = mInit;
      const char* kbase = sK[buf];
      __builtin_amdgcn_s_setprio(1);
#pragma unroll
      for (int ks = 0; ks < 4; ++ks) {
        const int swz = (ks * 32 + hi * 16) ^ ((l31 & 7) << 4);
        bf16x8 kf0 = *(const bf16x8*)(kbase + l31 * 128 + swz);
        bf16x8 kf1 = *(const bf16x8*)(kbase + (32 + l31) * 128 + swz);
        sA0 = __builtin_amdgcn_mfma_f32_32x32x16_bf16(kf0, qfA[ks], sA0, 0, 0, 0);
        sB0 = __builtin_amdgcn_mfma_f32_32x32x16_bf16(kf0, qfB[ks], sB0, 0, 0, 0);
        sA1 = __builtin_amdgcn_mfma_f32_32x32x16_bf16(kf1, qfA[ks], sA1, 0, 0, 0);
        sB1 = __builtin_amdgcn_mfma_f32_32x32x16_bf16(kf1, qfB[ks], sB1, 0, 0, 0);
      }
      __builtin_amdgcn_s_setprio(0);

      // ---- p = 2^s, parallel partial sums (groups independent)
      {
        float a0 = 0.f, a1 = 0.f, b0 = 0.f, b1 = 0.f;
#pragma unroll
        for (int i = 0; i < 16; i += 2) {
          float pa0 = __builtin_amdgcn_exp2f(sA0[i + 0]); sA0[i + 0] = pa0; a0 += pa0;
          float pa1 = __builtin_amdgcn_exp2f(sA0[i + 1]); sA0[i + 1] = pa1; a1 += pa1;
          float pb0 = __builtin_amdgcn_exp2f(sB0[i + 0]); sB0[i + 0] = pb0; b0 += pb0;
          float pb1 = __builtin_amdgcn_exp2f(sB0[i + 1]); sB0[i + 1] = pb1; b1 += pb1;
        }
#pragma unroll
        for (int i = 0; i < 16; i += 2) {
          float pa0 = __builtin_amdgcn_exp2f(sA1[i + 0]); sA1[i + 0] = pa0; a0 += pa0;
          float pa1 = __builtin_amdgcn_exp2f(sA1[i + 1]); sA1[i + 1] = pa1; a1 += pa1;
          float pb0 = __builtin_amdgcn_exp2f(sB1[i + 0]); sB1[i + 0] = pb0; b0 += pb0;
          float pb1 = __builtin_amdgcn_exp2f(sB1[i + 1]); sB1[i + 1] = pb1; b1 += pb1;
        }
        lA += a0 + a1;
        lB += b0 + b1;
      }

      // ---- O^T += Vt . P^T  (vf read once, used by both groups)
      const char* vbase = sV[buf];
#pragma unroll
      for (int sl = 0; sl < 4; ++sl) {
        const f32x16& spA = (sl < 2) ? sA0 : sA1;
        const f32x16& spB = (sl < 2) ? sB0 : sB1;
        const int s8 = (sl & 1) * 8;
        // group A: in-register cross-half exchange via permlane32_swap
        uint32_t ax0 = cvtpk_bf16(spA[s8 + 0], spA[s8 + 1]);
        uint32_t ax1 = cvtpk_bf16(spA[s8 + 2], spA[s8 + 3]);
        uint32_t ay0 = cvtpk_bf16(spA[s8 + 4], spA[s8 + 5]);
        uint32_t ay1 = cvtpk_bf16(spA[s8 + 6], spA[s8 + 7]);
        u32x2 ra0 = __builtin_amdgcn_permlane32_swap(ax0, ay0, false, false);
        u32x2 ra1 = __builtin_amdgcn_permlane32_swap(ax1, ay1, false, false);
        u32x4 wvA;
        wvA[0] = ra0[0];   // keys base+0,1
        wvA[1] = ra1[0];   // keys base+2,3
        wvA[2] = ra0[1];   // keys base+4,5
        wvA[3] = ra1[1];   // keys base+6,7
        bf16x8 pfA = __builtin_bit_cast(bf16x8, wvA);
        // group B
        uint32_t bx0 = cvtpk_bf16(spB[s8 + 0], spB[s8 + 1]);
        uint32_t bx1 = cvtpk_bf16(spB[s8 + 2], spB[s8 + 3]);
        uint32_t by0 = cvtpk_bf16(spB[s8 + 4], spB[s8 + 5]);
        uint32_t by1 = cvtpk_bf16(spB[s8 + 6], spB[s8 + 7]);
        u32x2 rb0 = __builtin_amdgcn_permlane32_swap(bx0, by0, false, false);
        u32x2 rb1 = __builtin_amdgcn_permlane32_swap(bx1, by1, false, false);
        u32x4 wvB;
        wvB[0] = rb0[0];
        wvB[1] = rb1[0];
        wvB[2] = rb0[1];
        wvB[3] = rb1[1];
        bf16x8 pfB = __builtin_bit_cast(bf16x8, wvB);

        const int swz = (sl * 32 + hi * 16) ^ ((l31 & 7) << 4);
        bf16x8 vf0 = *(const bf16x8*)(vbase + l31 * 128 + swz);
        bf16x8 vf1 = *(const bf16x8*)(vbase + (32 + l31) * 128 + swz);
        __builtin_amdgcn_s_setprio(1);
        oA0 = __builtin_amdgcn_mfma_f32_32x32x16_bf16(vf0, pfA, oA0, 0, 0, 0);
        oB0 = __builtin_amdgcn_mfma_f32_32x32x16_bf16(vf0, pfB, oB0, 0, 0, 0);
        oA1 = __builtin_amdgcn_mfma_f32_32x32x16_bf16(vf1, pfA, oA1, 0, 0, 0);
        oB1 = __builtin_amdgcn_mfma_f32_32x32x16_bf16(vf1, pfB, oB1, 0, 0, 0);
        __builtin_amdgcn_s_setprio(0);
      }
    }
    __syncthreads();
  }
#undef STAGE1

  // ---- epilogue: O^T[d][q], lane q = l31; d = dt*32 + rg*8 + hi*4 + i
  float ltA = lA + __shfl_xor(lA, 32);
  float ltB = lB + __shfl_xor(lB, 32);
  float invA = 1.0f / ltA, invB = 1.0f / ltB;
  unsigned short* orowA = Ctx + ((size_t)b * SEQ + q0 + wave * 64 + l31) * DM + h * 64;
  unsigned short* orowB = orowA + (size_t)32 * DM;
#pragma unroll
  for (int dt = 0; dt < 2; ++dt) {
    const f32x16& oa = dt ? oA1 : oA0;
    const f32x16& ob = dt ? oB1 : oB0;
#pragma unroll
    for (int rg = 0; rg < 4; ++rg) {
      u16x4 pkA, pkB;
#pragma unroll
      for (int i = 0; i < 4; ++i) {
        pkA[i] = f2bf(oa[rg * 4 + i] * invA);
        pkB[i] = f2bf(ob[rg * 4 + i] * invB);
      }
      *(u16x4*)(orowA + dt * 32 + rg * 8 + hi * 4) = pkA;
      *(u16x4*)(orowB + dt * 32 + rg * 8 + hi * 4) = pkB;
    }
  }
}

extern "C" void kernel_launch(void* const* d_in, const int* in_sizes, int n_in,
                              void* d_out, int out_size, void* d_ws, size_t ws_size,
                              hipStream_t stream) {
  const float* query = (const float*)d_in[0];
  const float* key   = (const float*)d_in[1];
  const float* value = (const float*)d_in[2];
  const float* Wq = (const float*)d_in[3];
  const float* bq = (const float*)d_in[4];
  const float* Wk = (const float*)d_in[5];
  const float* bk = (const float*)d_in[6];
  const float* Wv = (const float*)d_in[7];
  const float* bv = (const float*)d_in[8];
  const float* Wo = (const float*)d_in[9];
  const float* bo = (const float*)d_in[10];

  const float QSCALE = 0.125f * 1.44269504088896340736f;
  char* ws = (char*)d_ws;
  const size_t MB = 1048576;

  prep_w<<<dim3(32, 32, 4), 256, 0, stream>>>(Wq, Wk, Wv, Wo, (unsigned short*)ws);
  unsigned short* Wt = (unsigned short*)ws;   // 8 MB

  if (ws_size >= 104 * MB) {
    // batched path: Wt@0, Xall@8MB (48MB), Qb@56, Kb@72, Vt@88; Xc reuses Xall
    unsigned short* Xall = (unsigned short*)(ws + 8 * MB);
    unsigned short* Qb   = (unsigned short*)(ws + 56 * MB);
    unsigned short* Kb   = (unsigned short*)(ws + 72 * MB);
    unsigned short* Vt   = (unsigned short*)(ws + 88 * MB);
    unsigned short* Xc   = Xall;              // dead after gemm_qkv

    cvt3<<<dim3(4096, 3), 256, 0, stream>>>(query, key, value, Xall);
    gemm_qkv<<<dim3(64, 8, 3), 256, 0, stream>>>(Xall, Wt, bq, bk, bv,
                                                 Qb, Kb, Vt, QSCALE);
    attn<<<dim3(64, 4), 512, 0, stream>>>(Qb, Kb, Vt, Xc);
    gemm_bt<1><<<dim3(64, 8), 256, 0, stream>>>(Xc, Wt + (size_t)3 * 1048576, bo, d_out, 1.0f);
  } else {
    // fallback 72MB layout: Qb@8, Kb@24, Vt@40, Xc@56; reuse Xc as X buffer
    unsigned short* Qb = (unsigned short*)(ws + 8 * MB);
    unsigned short* Kb = (unsigned short*)(ws + 24 * MB);
    unsigned short* Vt = (unsigned short*)(ws + 40 * MB);
    unsigned short* Xc = (unsigned short*)(ws + 56 * MB);

    cvt3<<<dim3(4096, 1), 256, 0, stream>>>(query, query, query, Xc);
    gemm_bt<0><<<dim3(64, 8), 256, 0, stream>>>(Xc, Wt, bq, Qb, QSCALE);
    cvt3<<<dim3(4096, 1), 256, 0, stream>>>(key, key, key, Xc);
    gemm_bt<0><<<dim3(64, 8), 256, 0, stream>>>(Xc, Wt + (size_t)1048576, bk, Kb, 1.0f);
    cvt3<<<dim3(4096, 1), 256, 0, stream>>>(value, value, value, Xc);
    gemm_bt<2><<<dim3(64, 8), 256, 0, stream>>>(Xc, Wt + (size_t)2 * 1048576, bv, Vt, 1.0f);
    attn<<<dim3(64, 4), 512, 0, stream>>>(Qb, Kb, Vt, Xc);
    gemm_bt<1><<<dim3(64, 8), 256, 0, stream>>>(Xc, Wt + (size_t)3 * 1048576, bo, d_out, 1.0f);
  }
}